// Round 8
// baseline (110.343 us; speedup 1.0000x reference)
//
#include <hip/hip_runtime.h>

// RelativePositionEncoding (AF3-style), B=1, N=1024, C_Z=128.
// out[i,j,c] = W_pos[d_res][c] + W_tok[d_tok][c] + same_ent*w_ent[c] + W_chn[d_chain][c]
// W rows: [0:66) pos, [66:132) tok, 132 ent, [133:139) chain.  IN_DIM=139.
//
// R8 change vs R4 (101.4us best): LOW occupancy — 256 blocks x 512 threads
// = 8 waves/CU (25%), mimicking fillBufferAligned's low-occupancy profile
// (10.9%, 6.7 TB/s). 4 rows i per block; 2 rows interleaved per loop body +
// unroll 2 for latency coverage. Inner math identical to R4.

typedef float f4 __attribute__((ext_vector_type(4)));

constexpr int kN     = 1024;
constexpr int kRowF4 = 32;             // 128 floats = 32 x f4 per W row
constexpr int kWF4   = 139 * kRowF4;   // 4448 f4 elements
constexpr int kThr   = 512;
constexpr int kRows  = 4;              // rows i per block

__global__ __launch_bounds__(kThr) void relpos_kernel(
    const int* __restrict__ asym,
    const int* __restrict__ resi,
    const int* __restrict__ ent,
    const int* __restrict__ sym,
    const int* __restrict__ tok,
    const float* __restrict__ W,
    float* __restrict__ out)
{
    __shared__ f4  sW[kWF4];     // 71,168 B
    __shared__ int sKey[kN];     //  4,096 B

    const int tid = threadIdx.x;
    const f4* __restrict__ W4 = reinterpret_cast<const f4*>(W);

    // Stage W into LDS; fold w_ent (row 132) into chain rows 133..137
    // (same_ent <=> d_chain <= 4, so those rows always get +w_ent).
    for (int idx = tid; idx < kWF4; idx += kThr) {
        f4 v = W4[idx];
        if (idx >= 133 * kRowF4 && idx < 138 * kRowF4)
            v += W4[132 * kRowF4 + (idx & (kRowF4 - 1))];
        sW[idx] = v;
    }
    // Pack per-j indices: asym(2) | ent(2) | sym(2) | resi(9) | tok(10)
    for (int j = tid; j < kN; j += kThr) {
        sKey[j] = (asym[j] & 3) | ((ent[j] & 3) << 2) | ((sym[j] & 3) << 4)
                | ((resi[j] & 511) << 6) | ((tok[j] & 1023) << 15);
    }
    __syncthreads();

    const int c4 = tid & 31;   // f4 column within the 128-wide channel dim
    const int jg = tid >> 5;   // 0..15 : j sub-index per iteration

    f4* __restrict__ out4 = reinterpret_cast<f4*>(out);

    const int i0 = blockIdx.x * kRows;
    #pragma unroll
    for (int ip = 0; ip < kRows / 2; ++ip) {
        const int ia = i0 + ip * 2;
        const int ib = ia + 1;
        const int aA = asym[ia], rA = resi[ia], eA = ent[ia], sA = sym[ia], tA = tok[ia];
        const int aB = asym[ib], rB = resi[ib], eB = ent[ib], sB = sym[ib], tB = tok[ib];
        f4* __restrict__ oA = out4 + (size_t)ia * kN * kRowF4 + c4;
        f4* __restrict__ oB = oA + (size_t)kN * kRowF4;

        #pragma unroll 2
        for (int it = 0; it < kN / 16; ++it) {
            const int j = it * 16 + jg;
            const int k = sKey[j];                 // broadcast ds_read_b32
            const int aj =  k        & 3;
            const int ej = (k >> 2)  & 3;
            const int sj = (k >> 4)  & 3;
            const int rj = (k >> 6)  & 511;
            const int tj = (k >> 15) & 1023;

            // row A
            {
                int dres = min(max(rA - rj + 32, 0), 64);
                if (aA != aj) dres = 65;
                int dtok = min(max(tA - tj + 32, 0), 64);
                if (!(aA == aj && rA == rj)) dtok = 65;
                int dchn = min(max(sA - sj + 2, 0), 4);
                if (eA != ej) dchn = 5;
                const f4 v = sW[dres * kRowF4 + c4]
                           + sW[(66 + dtok) * kRowF4 + c4]
                           + sW[(133 + dchn) * kRowF4 + c4];
                oA[(size_t)j * kRowF4] = v;
            }
            // row B
            {
                int dres = min(max(rB - rj + 32, 0), 64);
                if (aB != aj) dres = 65;
                int dtok = min(max(tB - tj + 32, 0), 64);
                if (!(aB == aj && rB == rj)) dtok = 65;
                int dchn = min(max(sB - sj + 2, 0), 4);
                if (eB != ej) dchn = 5;
                const f4 v = sW[dres * kRowF4 + c4]
                           + sW[(66 + dtok) * kRowF4 + c4]
                           + sW[(133 + dchn) * kRowF4 + c4];
                oB[(size_t)j * kRowF4] = v;
            }
        }
    }
}

extern "C" void kernel_launch(void* const* d_in, const int* in_sizes, int n_in,
                              void* d_out, int out_size, void* d_ws, size_t ws_size,
                              hipStream_t stream) {
    const int*   asym = (const int*)d_in[0];
    const int*   resi = (const int*)d_in[1];
    const int*   ent  = (const int*)d_in[2];
    const int*   sym  = (const int*)d_in[3];
    const int*   tok  = (const int*)d_in[4];
    const float* W    = (const float*)d_in[5];
    float*       out  = (float*)d_out;

    relpos_kernel<<<dim3(kN / kRows), dim3(kThr), 0, stream>>>(asym, resi, ent, sym, tok, W, out);
}